// Round 2
// baseline (55.692 us; speedup 1.0000x reference)
//
#include <hip/hip_runtime.h>
#include <math.h>

#define B_ 4
#define T_ 512
#define D_ 2048
#define H_ 1024
#define E_ 2

#define LD4(p) (*reinterpret_cast<const float4*>(p))

__device__ __forceinline__ float waveReduceSum(float v) {
    #pragma unroll
    for (int o = 32; o > 0; o >>= 1) v += __shfl_down(v, o, 64);
    return v;
}

// K1: w2s[row] = sum_d W2[row, d], row = e*H+h (2048 rows; one wave per row).
// Also zeroes the completion counter used by K3 (fresh every call -> graph-safe).
__global__ __launch_bounds__(256) void k_prep(const float* __restrict__ W2,
                                              float* __restrict__ w2s,
                                              int* __restrict__ counter) {
    if (blockIdx.x == 0 && threadIdx.x == 0) *counter = 0;
    int gw   = (blockIdx.x * 256 + threadIdx.x) >> 6;   // 0..2047
    int lane = threadIdx.x & 63;
    const float* p = W2 + (size_t)gw * D_;
    float acc = 0.f;
    #pragma unroll
    for (int k = 0; k < D_ / 256; ++k) {                // 8 float4 per lane
        float4 a = LD4(p + (lane + k * 64) * 4);
        acc += (a.x + a.y) + (a.z + a.w);
    }
    acc = waveReduceSum(acc);
    if (lane == 0) w2s[gw] = acc;
}

// K2: v[e,d] = sum_h W1[e,d,h]*w2s[e,h]  (4096 rows; one wave per row).
// Blocks 1024/1025 compute c[e] = sum_h b1[e,h]*w2s[e,h] + sum_d b2[e,d].
__global__ __launch_bounds__(256) void k_vred(const float* __restrict__ W1,
                                              const float* __restrict__ w2s,
                                              const float* __restrict__ b1,
                                              const float* __restrict__ b2,
                                              float* __restrict__ v,
                                              float* __restrict__ c) {
    if (blockIdx.x >= 1024) {
        __shared__ float lds[4];
        int e = blockIdx.x - 1024;
        float acc = 0.f;
        for (int i = threadIdx.x; i < H_; i += 256) acc += b1[e * H_ + i] * w2s[e * H_ + i];
        for (int i = threadIdx.x; i < D_; i += 256) acc += b2[e * D_ + i];
        acc = waveReduceSum(acc);
        if ((threadIdx.x & 63) == 0) lds[threadIdx.x >> 6] = acc;
        __syncthreads();
        if (threadIdx.x == 0) c[e] = lds[0] + lds[1] + lds[2] + lds[3];
        return;
    }
    int row  = (blockIdx.x * 256 + threadIdx.x) >> 6;   // 0..4095 (= e*D_ + d)
    int lane = threadIdx.x & 63;
    int e    = row >> 11;                               // row / D_
    const float* p = W1 + (size_t)row * H_;
    const float* w = w2s + e * H_;
    float acc = 0.f;
    #pragma unroll
    for (int k = 0; k < H_ / 256; ++k) {                // 4 float4 per lane
        float4 a = LD4(p + (lane + k * 64) * 4);
        float4 b = LD4(w + (lane + k * 64) * 4);
        acc += a.x * b.x + a.y * b.y + a.z * b.z + a.w * b.w;
    }
    acc = waveReduceSum(acc);
    if (lane == 0) v[row] = acc;
}

// K3: per token (one wave per token): gate logits + both expert dots in one x pass,
// s[bt] = gate * (dot[idx] + c[idx]). Last finished block computes the per-batch
// log_softmax over T and writes d_out (wave w handles batch w).
__global__ __launch_bounds__(256) void k_token(const float* __restrict__ x,
                                               const float* __restrict__ Wg,
                                               const float* __restrict__ v,
                                               const float* __restrict__ c,
                                               float* __restrict__ s,
                                               float* __restrict__ out,
                                               int* __restrict__ counter) {
    int lane = threadIdx.x & 63;
    int bt   = (blockIdx.x * 256 + threadIdx.x) >> 6;   // 0..2047
    const float* xp = x + (size_t)bt * D_;
    float g0 = 0.f, g1 = 0.f, d0 = 0.f, d1 = 0.f;
    #pragma unroll
    for (int k = 0; k < D_ / 256; ++k) {                // 8 iterations
        int i = (lane + k * 64) * 4;
        float4 xv = LD4(xp + i);
        float4 v0 = LD4(v + i);
        float4 v1 = LD4(v + D_ + i);
        float4 wa = LD4(Wg + 2 * i);                    // d=i, i+1
        float4 wb = LD4(Wg + 2 * i + 4);                // d=i+2, i+3
        g0 += xv.x * wa.x + xv.y * wa.z + xv.z * wb.x + xv.w * wb.z;
        g1 += xv.x * wa.y + xv.y * wa.w + xv.z * wb.y + xv.w * wb.w;
        d0 += xv.x * v0.x + xv.y * v0.y + xv.z * v0.z + xv.w * v0.w;
        d1 += xv.x * v1.x + xv.y * v1.y + xv.z * v1.z + xv.w * v1.w;
    }
    #pragma unroll
    for (int o = 32; o > 0; o >>= 1) {
        g0 += __shfl_down(g0, o, 64);
        g1 += __shfl_down(g1, o, 64);
        d0 += __shfl_down(d0, o, 64);
        d1 += __shfl_down(d1, o, 64);
    }
    if (lane == 0) {
        int e = (g1 > g0) ? 1 : 0;                      // argmax, first index on tie
        float m = fmaxf(g0, g1);
        float p0 = expf(g0 - m), p1 = expf(g1 - m);
        float gate = ((e == 0) ? p0 : p1) / (p0 + p1);
        float dot = (e == 0) ? d0 : d1;
        s[bt] = gate * (dot + c[e]);
        __threadfence();                                 // release s write
    }
    __syncthreads();
    __shared__ int isLast;
    if (threadIdx.x == 0) {
        int old = atomicAdd(counter, 1);
        isLast = (old == (int)gridDim.x - 1) ? 1 : 0;
    }
    __syncthreads();
    if (!isLast) return;
    __threadfence();                                     // acquire all s writes
    int b = threadIdx.x >> 6;                            // wave -> batch
    const float* sb = s + b * T_;
    float vals[T_ / 64];
    float m = -INFINITY;
    #pragma unroll
    for (int k = 0; k < T_ / 64; ++k) {                  // 8 per lane
        vals[k] = sb[lane + k * 64];
        m = fmaxf(m, vals[k]);
    }
    #pragma unroll
    for (int o = 1; o < 64; o <<= 1) m = fmaxf(m, __shfl_xor(m, o, 64));
    float sum = 0.f;
    #pragma unroll
    for (int k = 0; k < T_ / 64; ++k) sum += expf(vals[k] - m);
    #pragma unroll
    for (int o = 1; o < 64; o <<= 1) sum += __shfl_xor(sum, o, 64);
    float lse = m + logf(sum);
    #pragma unroll
    for (int k = 0; k < T_ / 64; ++k) out[b * T_ + lane + k * 64] = vals[k] - lse;
}

extern "C" void kernel_launch(void* const* d_in, const int* in_sizes, int n_in,
                              void* d_out, int out_size, void* d_ws, size_t ws_size,
                              hipStream_t stream) {
    (void)in_sizes; (void)n_in; (void)out_size; (void)ws_size;
    const float* x  = (const float*)d_in[0];
    const float* Wg = (const float*)d_in[1];
    const float* W1 = (const float*)d_in[2];
    const float* b1 = (const float*)d_in[3];
    const float* W2 = (const float*)d_in[4];
    const float* b2 = (const float*)d_in[5];
    float* out = (float*)d_out;

    float* ws   = (float*)d_ws;
    float* w2s  = ws;                    // [E,H]  2048 floats
    float* v    = ws + 2048;             // [E,D]  4096 floats
    float* c    = ws + 6144;             // [E]    2 floats
    int*   ctr  = (int*)(ws + 6148);     // 1 int
    float* s    = ws + 6160;             // [B,T]  2048 floats, 16B-aligned

    k_prep <<<512,  256, 0, stream>>>(W2, w2s, ctr);
    k_vred <<<1026, 256, 0, stream>>>(W1, w2s, b1, b2, v, c);
    k_token<<<512,  256, 0, stream>>>(x, Wg, v, c, s, out, ctr);
}

// Round 3
// 24.136 us; speedup vs baseline: 2.3074x; 2.3074x over previous
//
#include <hip/hip_runtime.h>
#include <math.h>

#define B_ 4
#define T_ 512
#define D_ 2048
#define H_ 1024
#define E_ 2

#define LD4(p) (*reinterpret_cast<const float4*>(p))

__device__ __forceinline__ float waveReduceSum(float v) {
    #pragma unroll
    for (int o = 32; o > 0; o >>= 1) v += __shfl_down(v, o, 64);
    return v;
}

// K1: w2s[row] = sum_d W2[row, d], row = e*H+h (2048 rows; one wave per row).
__global__ __launch_bounds__(256) void k_w2sum(const float* __restrict__ W2,
                                               float* __restrict__ w2s) {
    int gw   = (blockIdx.x * 256 + threadIdx.x) >> 6;   // 0..2047
    int lane = threadIdx.x & 63;
    const float* p = W2 + (size_t)gw * D_;
    float acc = 0.f;
    #pragma unroll
    for (int k = 0; k < D_ / 256; ++k) {                // 8 float4 per lane
        float4 a = LD4(p + (lane + k * 64) * 4);
        acc += (a.x + a.y) + (a.z + a.w);
    }
    acc = waveReduceSum(acc);
    if (lane == 0) w2s[gw] = acc;
}

// K2: v[e,d] = sum_h W1[e,d,h]*w2s[e,h]  (4096 rows; one wave per row).
// Blocks 1024/1025 compute c[e] = sum_h b1[e,h]*w2s[e,h] + sum_d b2[e,d].
__global__ __launch_bounds__(256) void k_vred(const float* __restrict__ W1,
                                              const float* __restrict__ w2s,
                                              const float* __restrict__ b1,
                                              const float* __restrict__ b2,
                                              float* __restrict__ v,
                                              float* __restrict__ c) {
    if (blockIdx.x >= 1024) {
        __shared__ float lds[4];
        int e = blockIdx.x - 1024;
        float acc = 0.f;
        for (int i = threadIdx.x; i < H_; i += 256) acc += b1[e * H_ + i] * w2s[e * H_ + i];
        for (int i = threadIdx.x; i < D_; i += 256) acc += b2[e * D_ + i];
        acc = waveReduceSum(acc);
        if ((threadIdx.x & 63) == 0) lds[threadIdx.x >> 6] = acc;
        __syncthreads();
        if (threadIdx.x == 0) c[e] = lds[0] + lds[1] + lds[2] + lds[3];
        return;
    }
    int row  = (blockIdx.x * 256 + threadIdx.x) >> 6;   // 0..4095 (= e*D_ + d)
    int lane = threadIdx.x & 63;
    int e    = row >> 11;                               // row / D_
    const float* p = W1 + (size_t)row * H_;
    const float* w = w2s + e * H_;
    float acc = 0.f;
    #pragma unroll
    for (int k = 0; k < H_ / 256; ++k) {                // 4 float4 per lane
        float4 a = LD4(p + (lane + k * 64) * 4);
        float4 b = LD4(w + (lane + k * 64) * 4);
        acc += a.x * b.x + a.y * b.y + a.z * b.z + a.w * b.w;
    }
    acc = waveReduceSum(acc);
    if (lane == 0) v[row] = acc;
}

// K3: per token (one wave per token): gate logits + both expert dots in one x pass,
// s[bt] = gate * (dot[idx] + c[idx]).  No fences, no atomics.
__global__ __launch_bounds__(256) void k_token(const float* __restrict__ x,
                                               const float* __restrict__ Wg,
                                               const float* __restrict__ v,
                                               const float* __restrict__ c,
                                               float* __restrict__ s) {
    int lane = threadIdx.x & 63;
    int bt   = (blockIdx.x * 256 + threadIdx.x) >> 6;   // 0..2047
    const float* xp = x + (size_t)bt * D_;
    float g0 = 0.f, g1 = 0.f, d0 = 0.f, d1 = 0.f;
    #pragma unroll
    for (int k = 0; k < D_ / 256; ++k) {                // 8 iterations
        int i = (lane + k * 64) * 4;
        float4 xv = LD4(xp + i);
        float4 v0 = LD4(v + i);
        float4 v1 = LD4(v + D_ + i);
        float4 wa = LD4(Wg + 2 * i);                    // d=i, i+1
        float4 wb = LD4(Wg + 2 * i + 4);                // d=i+2, i+3
        g0 += xv.x * wa.x + xv.y * wa.z + xv.z * wb.x + xv.w * wb.z;
        g1 += xv.x * wa.y + xv.y * wa.w + xv.z * wb.y + xv.w * wb.w;
        d0 += xv.x * v0.x + xv.y * v0.y + xv.z * v0.z + xv.w * v0.w;
        d1 += xv.x * v1.x + xv.y * v1.y + xv.z * v1.z + xv.w * v1.w;
    }
    #pragma unroll
    for (int o = 32; o > 0; o >>= 1) {
        g0 += __shfl_down(g0, o, 64);
        g1 += __shfl_down(g1, o, 64);
        d0 += __shfl_down(d0, o, 64);
        d1 += __shfl_down(d1, o, 64);
    }
    if (lane == 0) {
        int e = (g1 > g0) ? 1 : 0;                      // argmax, first index on tie
        float m = fmaxf(g0, g1);
        float p0 = expf(g0 - m), p1 = expf(g1 - m);
        float gate = ((e == 0) ? p0 : p1) / (p0 + p1);
        float dot = (e == 0) ? d0 : d1;
        s[bt] = gate * (dot + c[e]);
    }
}

// K4: out[b,t] = s[b,t] - max_t - log(sum_t exp(s - max_t)).  One block (512 thr) per b.
__global__ void k_lsm(const float* __restrict__ s, float* __restrict__ out) {
    __shared__ float lds[8];
    int b = blockIdx.x;
    int t = threadIdx.x;                        // 512 threads, 8 waves
    int lane = t & 63, wid = t >> 6;
    float val = s[b * T_ + t];

    float m = val;
    #pragma unroll
    for (int o = 1; o < 64; o <<= 1) m = fmaxf(m, __shfl_xor(m, o, 64));
    if (lane == 0) lds[wid] = m;
    __syncthreads();
    m = lds[0];
    #pragma unroll
    for (int w = 1; w < 8; ++w) m = fmaxf(m, lds[w]);
    __syncthreads();

    float ex = expf(val - m);
    float sum = ex;
    #pragma unroll
    for (int o = 1; o < 64; o <<= 1) sum += __shfl_xor(sum, o, 64);
    if (lane == 0) lds[wid] = sum;
    __syncthreads();
    sum = 0.f;
    #pragma unroll
    for (int w = 0; w < 8; ++w) sum += lds[w];

    out[b * T_ + t] = val - m - logf(sum);
}

extern "C" void kernel_launch(void* const* d_in, const int* in_sizes, int n_in,
                              void* d_out, int out_size, void* d_ws, size_t ws_size,
                              hipStream_t stream) {
    (void)in_sizes; (void)n_in; (void)out_size; (void)ws_size;
    const float* x  = (const float*)d_in[0];
    const float* Wg = (const float*)d_in[1];
    const float* W1 = (const float*)d_in[2];
    const float* b1 = (const float*)d_in[3];
    const float* W2 = (const float*)d_in[4];
    const float* b2 = (const float*)d_in[5];
    float* out = (float*)d_out;

    float* ws  = (float*)d_ws;
    float* w2s = ws;                    // [E,H]  2048 floats
    float* v   = ws + 2048;             // [E,D]  4096 floats
    float* c   = ws + 6144;             // [E]    2 floats
    float* s   = ws + 6160;             // [B,T]  2048 floats, 16B-aligned

    k_w2sum<<<512,  256, 0, stream>>>(W2, w2s);
    k_vred <<<1026, 256, 0, stream>>>(W1, w2s, b1, b2, v, c);
    k_token<<<512,  256, 0, stream>>>(x, Wg, v, c, s);
    k_lsm  <<<B_,   512, 0, stream>>>(s, out);
}